// Round 8
// baseline (1752.870 us; speedup 1.0000x reference)
//
#include <hip/hip_runtime.h>

#define NN 50000
#define F_IN 17
#define HIDC 64
#define NLAYERS 12
#define NE 400000
#define NET (NE + NN)
#define EPS_BN 1e-5f

typedef unsigned short u16;
typedef __bf16 bf16x8 __attribute__((ext_vector_type(8)));
typedef float f32x4 __attribute__((ext_vector_type(4)));

__device__ __forceinline__ float bf2f(u16 v) {
    union { unsigned int i; float f; } u; u.i = ((unsigned int)v) << 16; return u.f;
}
__device__ __forceinline__ u16 f2bf(float f) {
    union { float f; unsigned int i; } u; u.f = f;
    unsigned int r = u.i + 0x7fffu + ((u.i >> 16) & 1u);
    return (u16)(r >> 16);
}
__device__ __forceinline__ float2 bf2x(unsigned int w) {
    union { unsigned int i; float f; } a, b;
    a.i = w << 16; b.i = w & 0xffff0000u;
    float2 r; r.x = a.f; r.y = b.f; return r;
}
__device__ __forceinline__ void unpack8(uint4 w, float* f) {
    float2 a = bf2x(w.x), b = bf2x(w.y), c = bf2x(w.z), d = bf2x(w.w);
    f[0] = a.x; f[1] = a.y; f[2] = b.x; f[3] = b.y;
    f[4] = c.x; f[5] = c.y; f[6] = d.x; f[7] = d.y;
}

__global__ void k_zero_i(int* __restrict__ p, int n) {
    int i = blockIdx.x * blockDim.x + threadIdx.x;
    if (i < n) p[i] = 0;
}
__global__ void k_zero_f(float* __restrict__ p, int n) {
    int i = blockIdx.x * blockDim.x + threadIdx.x;
    if (i < n) p[i] = 0.f;
}

// ---- transposed split-bf16 concat weights ----
__global__ void k_wt(const float* __restrict__ Wl, const float* __restrict__ Wr,
                     u16* __restrict__ WThi, u16* __restrict__ WTlo) {
    int t = blockIdx.x * blockDim.x + threadIdx.x;
    if (t >= NLAYERS * 256 * HIDC) return;
    int k = t & 63, j = (t >> 6) & 255, i = t >> 14;
    int jj = (j < 128) ? j : (j - 128);
    float v = (j < 128) ? Wl[(i * HIDC + k) * 128 + jj] : Wr[(i * HIDC + k) * 128 + jj];
    u16 hi = f2bf(v);
    u16 lo = f2bf(v - bf2f(hi));
    WThi[t] = hi; WTlo[t] = lo;
}

// ---- CSR build ----
__global__ void k_count(const int* __restrict__ ei, int* __restrict__ deg) {
    int e = blockIdx.x * blockDim.x + threadIdx.x;
    if (e < NE) {
        int d = ei[NE + e];
        if ((unsigned)d < NN) atomicAdd(&deg[d], 1);
    }
}

__global__ void k_scan1(const int* __restrict__ deg, int* __restrict__ tmp, int* __restrict__ part) {
    __shared__ int s[256];
    int b = blockIdx.x, t = threadIdx.x;
    int n = b * 256 + t;
    int v = (n < NN) ? deg[n] + 1 : 0;
    s[t] = v; __syncthreads();
    for (int o = 1; o < 256; o <<= 1) {
        int a = s[t];
        int w = (t >= o) ? s[t - o] : 0;
        __syncthreads();
        s[t] = a + w;
        __syncthreads();
    }
    if (n < NN) tmp[n] = s[t];
    if (t == 255) part[b] = s[255];
}
__global__ void k_scan2(int* __restrict__ part) {
    __shared__ int s[256];
    int t = threadIdx.x;
    int v = (t < 196) ? part[t] : 0;
    s[t] = v; __syncthreads();
    for (int o = 1; o < 256; o <<= 1) {
        int a = s[t];
        int w = (t >= o) ? s[t - o] : 0;
        __syncthreads();
        s[t] = a + w;
        __syncthreads();
    }
    if (t < 196) part[t] = s[t] - v;
    if (t == 195) part[196] = s[195];
}
__global__ void k_scan3(const int* __restrict__ deg, const int* __restrict__ tmp,
                        const int* __restrict__ part, int* __restrict__ rp, int* __restrict__ cur) {
    int b = blockIdx.x, t = threadIdx.x;
    int n = b * 256 + t;
    if (n < NN) {
        int e = tmp[n] - (deg[n] + 1) + part[b];
        rp[n] = e; cur[n] = e;
    }
    if (n == 0) rp[NN] = part[196];
}

__global__ void k_scatter(const int* __restrict__ ei, int* __restrict__ cur, int* __restrict__ col) {
    int e = blockIdx.x * blockDim.x + threadIdx.x;
    if (e >= NET) return;
    int s, d;
    if (e < NE) { s = ei[e]; d = ei[NE + e]; } else { s = d = e - NE; }
    if ((unsigned)s >= NN) s = 0;
    if ((unsigned)d >= NN) d = 0;
    int p = atomicAdd(&cur[d], 1);
    if ((unsigned)p < NET) col[p] = s;
}

// ---- input projection + BN partial sums ----
__global__ void k_inproj(const float* __restrict__ x, const float* __restrict__ W, const float* __restrict__ b,
                         float* __restrict__ g, float* __restrict__ bns) {
    __shared__ float ls[64], lq[64];
    int t = threadIdx.x;
    if (t < 64) { ls[t] = 0.f; lq[t] = 0.f; }
    __syncthreads();
    int j = t & 63;
    float wcol[F_IN];
#pragma unroll
    for (int k = 0; k < F_IN; k++) wcol[k] = W[k * 64 + j];
    float bias = b[j];
    float sA = 0.f, sQ = 0.f;
    for (int idx = blockIdx.x * blockDim.x + t; idx < NN * 64; idx += gridDim.x * blockDim.x) {
        int node = idx >> 6;
        float acc = bias;
#pragma unroll
        for (int k = 0; k < F_IN; k++) acc += x[node * F_IN + k] * wcol[k];
        g[idx] = acc;
        sA += acc; sQ += acc * acc;
    }
    atomicAdd(&ls[j], sA); atomicAdd(&lq[j], sQ);
    __syncthreads();
    if (t < 64) atomicAdd(&bns[t], ls[t]);
    else if (t < 128) atomicAdd(&bns[t], lq[t - 64]);
}

// ---- fused BN+ELU+residual prologue + xl|xr MFMA GEMM ----
#define LDP 72
__global__ __launch_bounds__(256) void k_gemmbn(const float* __restrict__ g, const float* __restrict__ bns,
                                                const float* __restrict__ gamma, const float* __restrict__ beta,
                                                float* h, int residual,
                                                const u16* __restrict__ WThi, const u16* __restrict__ WTlo,
                                                u16* __restrict__ xlxr) {
    __shared__ u16 shi[16 * LDP];
    __shared__ u16 slo[16 * LDP];
    int t = threadIdx.x;
    int node0 = blockIdx.x * 16;
    int lane = t & 63, wv = t >> 6;
    int ml = lane & 15, kb = (lane >> 4) * 8;
    bf16x8 bh[4][2], bl[4][2];
#pragma unroll
    for (int c = 0; c < 4; c++) {
        int col0 = (wv * 4 + c) * 16;
        size_t brow = (size_t)(col0 + ml) * 64 + kb;
        bh[c][0] = *(const bf16x8*)(WThi + brow);
        bh[c][1] = *(const bf16x8*)(WThi + brow + 32);
        bl[c][0] = *(const bf16x8*)(WTlo + brow);
        bl[c][1] = *(const bf16x8*)(WTlo + brow + 32);
    }
    {
        int nd = t >> 4, ch = (t & 15) * 4;
        size_t gpos = (size_t)(node0 + nd) * 64 + ch;
        float4 gg = *(const float4*)(g + gpos);
        float4 out;
#pragma unroll
        for (int r = 0; r < 4; r++) {
            int c = ch + r;
            float mean = bns[c] * (1.0f / NN);
            float var = bns[64 + c] * (1.0f / NN) - mean * mean;
            var = fmaxf(var, 0.f);
            float rstd = rsqrtf(var + EPS_BN);
            float v = ((&gg.x)[r] - mean) * rstd * gamma[c] + beta[c];
            (&out.x)[r] = v > 0.f ? v : (__expf(v) - 1.f);
        }
        if (residual) {
            float4 hh = *(const float4*)(h + gpos);
            out.x += hh.x; out.y += hh.y; out.z += hh.z; out.w += hh.w;
        }
        *(float4*)(h + gpos) = out;
        ushort4 phi, plo;
#pragma unroll
        for (int r = 0; r < 4; r++) {
            float v = (&out.x)[r];
            u16 hi = f2bf(v);
            u16 lo = f2bf(v - bf2f(hi));
            (&phi.x)[r] = hi; (&plo.x)[r] = lo;
        }
        *(ushort4*)(shi + nd * LDP + ch) = phi;
        *(ushort4*)(slo + nd * LDP + ch) = plo;
    }
    __syncthreads();
    int arow = ml * LDP + kb;
    bf16x8 ah0 = *(const bf16x8*)(shi + arow);
    bf16x8 ah1 = *(const bf16x8*)(shi + arow + 32);
    bf16x8 al0 = *(const bf16x8*)(slo + arow);
    bf16x8 al1 = *(const bf16x8*)(slo + arow + 32);
    int row = node0 + (lane >> 4) * 4;
#pragma unroll
    for (int c = 0; c < 4; c++) {
        f32x4 acc = {0.f, 0.f, 0.f, 0.f};
        acc = __builtin_amdgcn_mfma_f32_16x16x32_bf16(al0, bh[c][0], acc, 0, 0, 0);
        acc = __builtin_amdgcn_mfma_f32_16x16x32_bf16(al1, bh[c][1], acc, 0, 0, 0);
        acc = __builtin_amdgcn_mfma_f32_16x16x32_bf16(ah0, bl[c][0], acc, 0, 0, 0);
        acc = __builtin_amdgcn_mfma_f32_16x16x32_bf16(ah1, bl[c][1], acc, 0, 0, 0);
        acc = __builtin_amdgcn_mfma_f32_16x16x32_bf16(ah0, bh[c][0], acc, 0, 0, 0);
        acc = __builtin_amdgcn_mfma_f32_16x16x32_bf16(ah1, bh[c][1], acc, 0, 0, 0);
        int colj = (wv * 4 + c) * 16 + ml;
#pragma unroll
        for (int r = 0; r < 4; r++) xlxr[(size_t)(row + r) * 256 + colj] = f2bf(acc[r]);
    }
}

// ---- GATv2 attention v4: 1 dst per 16-lane subset, 3-deep prefetch ----
// lane = 16*gsub + q; lane handles channels 8q..8q+7; q<8 -> head0, q>=8 -> head1
// grid = NN/16 blocks exactly (3125); block covers dsts [blockIdx*16, blockIdx*16+16)
__global__ __launch_bounds__(256, 6) void k_edge(const uint4* __restrict__ xw4, const int* __restrict__ rp,
                                                 const int* __restrict__ col, const float* __restrict__ attL,
                                                 const float* __restrict__ cbL, float* __restrict__ g,
                                                 float* __restrict__ bns) {
    __shared__ float ls[64], lq[64];
    int t = threadIdx.x;
    if (t < 64) { ls[t] = 0.f; lq[t] = 0.f; }
    __syncthreads();
    int lane = t & 63;
    int q = lane & 15;
    int gsub = lane >> 4;
    int d = blockIdx.x * 16 + (t >> 6) * 4 + gsub;
    float atv[8];
#pragma unroll
    for (int i = 0; i < 8; i++) atv[i] = attL[8 * q + i];
    float xr[8];
    { uint4 w = xw4[(size_t)d * 32 + 16 + q]; unpack8(w, xr); }
    int beg = rp[d], end = rp[d + 1];
    float m = -1e30f, lsum = 0.f;
    float acc[8];
#pragma unroll
    for (int i = 0; i < 8; i++) acc[i] = 0.f;
    // 3-deep prefetch (deg >= 1 guaranteed by self-loop)
    int n1 = (beg + 1 < end) ? col[beg + 1] : 0;
    int n2 = (beg + 2 < end) ? col[beg + 2] : 0;
    uint4 w0 = xw4[(size_t)col[beg] * 32 + q];
    uint4 w1 = xw4[(size_t)n1 * 32 + q];
    uint4 w2 = xw4[(size_t)n2 * 32 + q];
    for (int idx = beg; idx < end; idx++) {
        uint4 cur = w0;
        w0 = w1; w1 = w2;
        if (idx + 3 < end) {
            int s3 = col[idx + 3];
            w2 = xw4[(size_t)s3 * 32 + q];
        }
        float xl[8]; unpack8(cur, xl);
        float p = 0.f;
#pragma unroll
        for (int i = 0; i < 8; i++) {
            float u = xl[i] + xr[i];
            float lr = u > 0.f ? u : 0.2f * u;
            p += lr * atv[i];
        }
        p += __shfl_xor(p, 1); p += __shfl_xor(p, 2); p += __shfl_xor(p, 4);
        float mn = fmaxf(m, p);
        float sc = __expf(m - mn);
        float pw = __expf(p - mn);
        lsum = lsum * sc + pw;
#pragma unroll
        for (int i = 0; i < 8; i++) acc[i] = acc[i] * sc + pw * xl[i];
        m = mn;
    }
    float inv = 1.0f / (lsum + 1e-16f);
#pragma unroll
    for (int i = 0; i < 8; i++) {
        float v = acc[i] * inv;
        acc[i] = 0.5f * (v + __shfl_xor(v, 8));  // head average
    }
    if (q < 8) {
        float4 wv0, wv1;
        float sl[8], ql[8];
#pragma unroll
        for (int i = 0; i < 8; i++) {
            float c = acc[i] + cbL[8 * q + i];
            sl[i] = c; ql[i] = c * c;
            if (i < 4) (&wv0.x)[i] = c; else (&wv1.x)[i - 4] = c;
        }
        *(float4*)(g + (size_t)d * 64 + 8 * q) = wv0;
        *(float4*)(g + (size_t)d * 64 + 8 * q + 4) = wv1;
#pragma unroll
        for (int i = 0; i < 8; i++) {
            atomicAdd(&ls[8 * q + i], sl[i]);
            atomicAdd(&lq[8 * q + i], ql[i]);
        }
    }
    __syncthreads();
    if (t < 64) atomicAdd(&bns[t], ls[t]);
    else if (t < 128) atomicAdd(&bns[t], lq[t - 64]);
}

// ---- final BN+ELU+residual (layer 12), h only ----
__global__ void k_bnfinal(const float* __restrict__ g, const float* __restrict__ bns,
                          const float* __restrict__ gamma, const float* __restrict__ beta, float* h) {
    int t = blockIdx.x * blockDim.x + threadIdx.x;
    if (t >= NN * 16) return;
    int c4 = (t & 15) * 4;
    float4 gg = *(const float4*)(g + (size_t)t * 4);
    float4 out;
#pragma unroll
    for (int r = 0; r < 4; r++) {
        int c = c4 + r;
        float mean = bns[c] * (1.0f / NN);
        float var = bns[64 + c] * (1.0f / NN) - mean * mean;
        var = fmaxf(var, 0.f);
        float rstd = rsqrtf(var + EPS_BN);
        float v = ((&gg.x)[r] - mean) * rstd * gamma[c] + beta[c];
        (&out.x)[r] = v > 0.f ? v : (__expf(v) - 1.f);
    }
    float4 hh = *(const float4*)(h + (size_t)t * 4);
    out.x += hh.x; out.y += hh.y; out.z += hh.z; out.w += hh.w;
    *(float4*)(h + (size_t)t * 4) = out;
}

// ---- output head ----
__global__ void k_head(const float* __restrict__ h, const float* __restrict__ W1, const float* __restrict__ b1,
                       const float* __restrict__ W2, const float* __restrict__ b2, float* __restrict__ out) {
    int t = blockIdx.x * blockDim.x + threadIdx.x;
    int node = t >> 5;
    int j = t & 31;
    if (node >= NN) return;
    float acc = b1[j];
    const float* hr = h + (size_t)node * 64;
#pragma unroll
    for (int k = 0; k < 64; k++) acc += hr[k] * W1[k * 32 + j];
    float e = acc > 0.f ? acc : (__expf(acc) - 1.f);
    float z = e * W2[j];
    z += __shfl_xor(z, 1); z += __shfl_xor(z, 2); z += __shfl_xor(z, 4);
    z += __shfl_xor(z, 8); z += __shfl_xor(z, 16);
    if (j == 0) {
        float y = z + b2[0];
        out[node] = 1.0f / (1.0f + __expf(-y));
    }
}

extern "C" void kernel_launch(void* const* d_in, const int* in_sizes, int n_in,
                              void* d_out, int out_size, void* d_ws, size_t ws_size,
                              hipStream_t stream) {
    const float* x = (const float*)d_in[0];
    const int* ei = (const int*)d_in[1];
    const float* inW = (const float*)d_in[2];
    const float* inb = (const float*)d_in[3];
    const float* ing = (const float*)d_in[4];
    const float* inbeta = (const float*)d_in[5];
    const float* Wl = (const float*)d_in[6];
    const float* Wr = (const float*)d_in[7];
    const float* att = (const float*)d_in[8];
    const float* cb = (const float*)d_in[9];
    const float* bng = (const float*)d_in[10];
    const float* bnb = (const float*)d_in[11];
    const float* W1 = (const float*)d_in[12];
    const float* b1 = (const float*)d_in[13];
    const float* W2 = (const float*)d_in[14];
    const float* b2 = (const float*)d_in[15];
    float* out = (float*)d_out;

    char* ws = (char*)d_ws;
    size_t off = 0;
    auto alloc = [&](size_t bytes) -> char* {
        char* p = ws + off;
        off = (off + bytes + 255) & ~(size_t)255;
        return p;
    };
    float* h    = (float*)alloc((size_t)NN * 64 * 4);
    float* g    = (float*)alloc((size_t)NN * 64 * 4);
    u16* xlxr   = (u16*)alloc((size_t)NN * 256 * 2);
    u16* WThi   = (u16*)alloc((size_t)NLAYERS * 256 * 64 * 2);
    u16* WTlo   = (u16*)alloc((size_t)NLAYERS * 256 * 64 * 2);
    int* deg    = (int*)alloc((size_t)NN * 4);
    int* rp     = (int*)alloc((size_t)(NN + 1) * 4);
    int* cur    = (int*)alloc((size_t)NN * 4);
    int* colv   = (int*)alloc((size_t)NET * 4);
    int* stmp   = (int*)alloc((size_t)NN * 4);
    int* part   = (int*)alloc(256 * 4);
    float* bns  = (float*)alloc((size_t)(NLAYERS + 1) * 128 * 4);

    k_zero_i<<<(NN + 255) / 256, 256, 0, stream>>>(deg, NN);
    k_zero_f<<<((NLAYERS + 1) * 128 + 255) / 256, 256, 0, stream>>>(bns, (NLAYERS + 1) * 128);

    k_wt<<<(NLAYERS * 256 * HIDC + 255) / 256, 256, 0, stream>>>(Wl, Wr, WThi, WTlo);
    k_count<<<(NE + 255) / 256, 256, 0, stream>>>(ei, deg);
    k_scan1<<<196, 256, 0, stream>>>(deg, stmp, part);
    k_scan2<<<1, 256, 0, stream>>>(part);
    k_scan3<<<196, 256, 0, stream>>>(deg, stmp, part, rp, cur);
    k_scatter<<<(NET + 255) / 256, 256, 0, stream>>>(ei, cur, colv);

    k_inproj<<<512, 256, 0, stream>>>(x, inW, inb, g, bns);

    for (int i = 0; i < NLAYERS; i++) {
        const float* gamma = (i == 0) ? ing : bng + (size_t)(i - 1) * 64;
        const float* beta  = (i == 0) ? inbeta : bnb + (size_t)(i - 1) * 64;
        k_gemmbn<<<3125, 256, 0, stream>>>(g, bns + (size_t)i * 128, gamma, beta, h, (i > 0) ? 1 : 0,
                                           WThi + (size_t)i * 16384, WTlo + (size_t)i * 16384, xlxr);
        k_edge<<<3125, 256, 0, stream>>>((const uint4*)xlxr, rp, colv,
                                         att + (size_t)i * 128, cb + (size_t)i * 64,
                                         g, bns + (size_t)(i + 1) * 128);
    }
    k_bnfinal<<<3125, 256, 0, stream>>>(g, bns + (size_t)NLAYERS * 128,
                                        bng + (size_t)(NLAYERS - 1) * 64, bnb + (size_t)(NLAYERS - 1) * 64, h);
    k_head<<<6250, 256, 0, stream>>>(h, W1, b1, W2, b2, out);
}

// Round 9
// 1196.667 us; speedup vs baseline: 1.4648x; 1.4648x over previous
//
#include <hip/hip_runtime.h>

#define NN 50000
#define F_IN 17
#define HIDC 64
#define NLAYERS 12
#define NE 400000
#define NET (NE + NN)
#define EPS_BN 1e-5f
#define NREP 8   // bns replicas to spread same-address atomic contention

typedef unsigned short u16;
typedef __bf16 bf16x8 __attribute__((ext_vector_type(8)));
typedef float f32x4 __attribute__((ext_vector_type(4)));

__device__ __forceinline__ float bf2f(u16 v) {
    union { unsigned int i; float f; } u; u.i = ((unsigned int)v) << 16; return u.f;
}
__device__ __forceinline__ u16 f2bf(float f) {
    union { float f; unsigned int i; } u; u.f = f;
    unsigned int r = u.i + 0x7fffu + ((u.i >> 16) & 1u);
    return (u16)(r >> 16);
}
__device__ __forceinline__ float2 bf2x(unsigned int w) {
    union { unsigned int i; float f; } a, b;
    a.i = w << 16; b.i = w & 0xffff0000u;
    float2 r; r.x = a.f; r.y = b.f; return r;
}
__device__ __forceinline__ void unpack8(uint4 w, float* f) {
    float2 a = bf2x(w.x), b = bf2x(w.y), c = bf2x(w.z), d = bf2x(w.w);
    f[0] = a.x; f[1] = a.y; f[2] = b.x; f[3] = b.y;
    f[4] = c.x; f[5] = c.y; f[6] = d.x; f[7] = d.y;
}

__global__ void k_zero_i(int* __restrict__ p, int n) {
    int i = blockIdx.x * blockDim.x + threadIdx.x;
    if (i < n) p[i] = 0;
}
__global__ void k_zero_f(float* __restrict__ p, int n) {
    int i = blockIdx.x * blockDim.x + threadIdx.x;
    if (i < n) p[i] = 0.f;
}

// ---- transposed split-bf16 concat weights ----
__global__ void k_wt(const float* __restrict__ Wl, const float* __restrict__ Wr,
                     u16* __restrict__ WThi, u16* __restrict__ WTlo) {
    int t = blockIdx.x * blockDim.x + threadIdx.x;
    if (t >= NLAYERS * 256 * HIDC) return;
    int k = t & 63, j = (t >> 6) & 255, i = t >> 14;
    int jj = (j < 128) ? j : (j - 128);
    float v = (j < 128) ? Wl[(i * HIDC + k) * 128 + jj] : Wr[(i * HIDC + k) * 128 + jj];
    u16 hi = f2bf(v);
    u16 lo = f2bf(v - bf2f(hi));
    WThi[t] = hi; WTlo[t] = lo;
}

// ---- CSR build ----
__global__ void k_count(const int* __restrict__ ei, int* __restrict__ deg) {
    int e = blockIdx.x * blockDim.x + threadIdx.x;
    if (e < NE) {
        int d = ei[NE + e];
        if ((unsigned)d < NN) atomicAdd(&deg[d], 1);
    }
}

__global__ void k_scan1(const int* __restrict__ deg, int* __restrict__ tmp, int* __restrict__ part) {
    __shared__ int s[256];
    int b = blockIdx.x, t = threadIdx.x;
    int n = b * 256 + t;
    int v = (n < NN) ? deg[n] + 1 : 0;
    s[t] = v; __syncthreads();
    for (int o = 1; o < 256; o <<= 1) {
        int a = s[t];
        int w = (t >= o) ? s[t - o] : 0;
        __syncthreads();
        s[t] = a + w;
        __syncthreads();
    }
    if (n < NN) tmp[n] = s[t];
    if (t == 255) part[b] = s[255];
}
__global__ void k_scan2(int* __restrict__ part) {
    __shared__ int s[256];
    int t = threadIdx.x;
    int v = (t < 196) ? part[t] : 0;
    s[t] = v; __syncthreads();
    for (int o = 1; o < 256; o <<= 1) {
        int a = s[t];
        int w = (t >= o) ? s[t - o] : 0;
        __syncthreads();
        s[t] = a + w;
        __syncthreads();
    }
    if (t < 196) part[t] = s[t] - v;
    if (t == 195) part[196] = s[195];
}
__global__ void k_scan3(const int* __restrict__ deg, const int* __restrict__ tmp,
                        const int* __restrict__ part, int* __restrict__ rp, int* __restrict__ cur) {
    int b = blockIdx.x, t = threadIdx.x;
    int n = b * 256 + t;
    if (n < NN) {
        int e = tmp[n] - (deg[n] + 1) + part[b];
        rp[n] = e; cur[n] = e;
    }
    if (n == 0) rp[NN] = part[196];
}

__global__ void k_scatter(const int* __restrict__ ei, int* __restrict__ cur, int* __restrict__ col) {
    int e = blockIdx.x * blockDim.x + threadIdx.x;
    if (e >= NET) return;
    int s, d;
    if (e < NE) { s = ei[e]; d = ei[NE + e]; } else { s = d = e - NE; }
    if ((unsigned)s >= NN) s = 0;
    if ((unsigned)d >= NN) d = 0;
    int p = atomicAdd(&cur[d], 1);
    if ((unsigned)p < NET) col[p] = s;
}

// ---- input projection + BN partial sums (into replica 0) ----
__global__ void k_inproj(const float* __restrict__ x, const float* __restrict__ W, const float* __restrict__ b,
                         float* __restrict__ g, float* __restrict__ bns) {
    __shared__ float ls[64], lq[64];
    int t = threadIdx.x;
    if (t < 64) { ls[t] = 0.f; lq[t] = 0.f; }
    __syncthreads();
    int j = t & 63;
    float wcol[F_IN];
#pragma unroll
    for (int k = 0; k < F_IN; k++) wcol[k] = W[k * 64 + j];
    float bias = b[j];
    float sA = 0.f, sQ = 0.f;
    for (int idx = blockIdx.x * blockDim.x + t; idx < NN * 64; idx += gridDim.x * blockDim.x) {
        int node = idx >> 6;
        float acc = bias;
#pragma unroll
        for (int k = 0; k < F_IN; k++) acc += x[node * F_IN + k] * wcol[k];
        g[idx] = acc;
        sA += acc; sQ += acc * acc;
    }
    atomicAdd(&ls[j], sA); atomicAdd(&lq[j], sQ);
    __syncthreads();
    if (t < 64) atomicAdd(&bns[t], ls[t]);
    else if (t < 128) atomicAdd(&bns[t], lq[t - 64]);
}

// ---- fused BN+ELU+residual prologue + xl|xr MFMA GEMM (folds NREP bns replicas) ----
#define LDP 72
__global__ __launch_bounds__(256) void k_gemmbn(const float* __restrict__ g, const float* __restrict__ bns,
                                                const float* __restrict__ gamma, const float* __restrict__ beta,
                                                float* h, int residual,
                                                const u16* __restrict__ WThi, const u16* __restrict__ WTlo,
                                                u16* __restrict__ xlxr) {
    __shared__ u16 shi[16 * LDP];
    __shared__ u16 slo[16 * LDP];
    __shared__ float sbn[128];
    int t = threadIdx.x;
    int node0 = blockIdx.x * 16;
    int lane = t & 63, wv = t >> 6;
    int ml = lane & 15, kb = (lane >> 4) * 8;
    // fold bns replicas into LDS
    if (t < 128) {
        float s = 0.f;
#pragma unroll
        for (int r = 0; r < NREP; r++) s += bns[r * 128 + t];
        sbn[t] = s;
    }
    bf16x8 bh[4][2], bl[4][2];
#pragma unroll
    for (int c = 0; c < 4; c++) {
        int col0 = (wv * 4 + c) * 16;
        size_t brow = (size_t)(col0 + ml) * 64 + kb;
        bh[c][0] = *(const bf16x8*)(WThi + brow);
        bh[c][1] = *(const bf16x8*)(WThi + brow + 32);
        bl[c][0] = *(const bf16x8*)(WTlo + brow);
        bl[c][1] = *(const bf16x8*)(WTlo + brow + 32);
    }
    __syncthreads();
    {
        int nd = t >> 4, ch = (t & 15) * 4;
        size_t gpos = (size_t)(node0 + nd) * 64 + ch;
        float4 gg = *(const float4*)(g + gpos);
        float4 out;
#pragma unroll
        for (int r = 0; r < 4; r++) {
            int c = ch + r;
            float mean = sbn[c] * (1.0f / NN);
            float var = sbn[64 + c] * (1.0f / NN) - mean * mean;
            var = fmaxf(var, 0.f);
            float rstd = rsqrtf(var + EPS_BN);
            float v = ((&gg.x)[r] - mean) * rstd * gamma[c] + beta[c];
            (&out.x)[r] = v > 0.f ? v : (__expf(v) - 1.f);
        }
        if (residual) {
            float4 hh = *(const float4*)(h + gpos);
            out.x += hh.x; out.y += hh.y; out.z += hh.z; out.w += hh.w;
        }
        *(float4*)(h + gpos) = out;
        ushort4 phi, plo;
#pragma unroll
        for (int r = 0; r < 4; r++) {
            float v = (&out.x)[r];
            u16 hi = f2bf(v);
            u16 lo = f2bf(v - bf2f(hi));
            (&phi.x)[r] = hi; (&plo.x)[r] = lo;
        }
        *(ushort4*)(shi + nd * LDP + ch) = phi;
        *(ushort4*)(slo + nd * LDP + ch) = plo;
    }
    __syncthreads();
    int arow = ml * LDP + kb;
    bf16x8 ah0 = *(const bf16x8*)(shi + arow);
    bf16x8 ah1 = *(const bf16x8*)(shi + arow + 32);
    bf16x8 al0 = *(const bf16x8*)(slo + arow);
    bf16x8 al1 = *(const bf16x8*)(slo + arow + 32);
    int row = node0 + (lane >> 4) * 4;
#pragma unroll
    for (int c = 0; c < 4; c++) {
        f32x4 acc = {0.f, 0.f, 0.f, 0.f};
        acc = __builtin_amdgcn_mfma_f32_16x16x32_bf16(al0, bh[c][0], acc, 0, 0, 0);
        acc = __builtin_amdgcn_mfma_f32_16x16x32_bf16(al1, bh[c][1], acc, 0, 0, 0);
        acc = __builtin_amdgcn_mfma_f32_16x16x32_bf16(ah0, bl[c][0], acc, 0, 0, 0);
        acc = __builtin_amdgcn_mfma_f32_16x16x32_bf16(ah1, bl[c][1], acc, 0, 0, 0);
        acc = __builtin_amdgcn_mfma_f32_16x16x32_bf16(ah0, bh[c][0], acc, 0, 0, 0);
        acc = __builtin_amdgcn_mfma_f32_16x16x32_bf16(ah1, bh[c][1], acc, 0, 0, 0);
        int colj = (wv * 4 + c) * 16 + ml;
#pragma unroll
        for (int r = 0; r < 4; r++) xlxr[(size_t)(row + r) * 256 + colj] = f2bf(acc[r]);
    }
}

// ---- GATv2 attention (r7 structure): 16-lane subset per dst slot, serial online softmax,
//      stats into replicated bns to avoid same-address atomic serialization ----
__global__ __launch_bounds__(256) void k_edge(const uint4* __restrict__ xw4, const int* __restrict__ rp,
                                              const int* __restrict__ col, const float* __restrict__ attL,
                                              const float* __restrict__ cbL, float* __restrict__ g,
                                              float* __restrict__ bns) {
    __shared__ float ls[64], lq[64];
    int t = threadIdx.x;
    if (t < 64) { ls[t] = 0.f; lq[t] = 0.f; }
    __syncthreads();
    int lane = t & 63;
    int q = lane & 15;
    int gsub = lane >> 4;
    int slot = (blockIdx.x * 4 + (t >> 6)) * 4 + gsub;
    int nslot = gridDim.x * 16;
    float atv[8];
#pragma unroll
    for (int i = 0; i < 8; i++) atv[i] = attL[8 * q + i];
    float cbv[8];
#pragma unroll
    for (int i = 0; i < 8; i++) cbv[i] = 0.f;
    if (q < 8) {
#pragma unroll
        for (int i = 0; i < 8; i++) cbv[i] = cbL[8 * q + i];
    }
    float sacc[8], qacc[8];
#pragma unroll
    for (int i = 0; i < 8; i++) { sacc[i] = 0.f; qacc[i] = 0.f; }
    for (int d = slot; d < NN; d += nslot) {
        float xr[8];
        { uint4 w = xw4[(size_t)d * 32 + 16 + q]; unpack8(w, xr); }
        int beg = rp[d], end = rp[d + 1];
        float m = -1e30f, lsum = 0.f;
        float acc[8];
#pragma unroll
        for (int i = 0; i < 8; i++) acc[i] = 0.f;
        int s0 = col[beg];  // deg >= 1 guaranteed (self-loop)
        uint4 xlw = xw4[(size_t)s0 * 32 + q];
        for (int idx = beg; idx < end; idx++) {
            uint4 curw = xlw;
            if (idx + 1 < end) {
                int s2 = col[idx + 1];
                xlw = xw4[(size_t)s2 * 32 + q];
            }
            float xl[8]; unpack8(curw, xl);
            float p = 0.f;
#pragma unroll
            for (int i = 0; i < 8; i++) {
                float u = xl[i] + xr[i];
                float lr = u > 0.f ? u : 0.2f * u;
                p += lr * atv[i];
            }
            p += __shfl_xor(p, 1); p += __shfl_xor(p, 2); p += __shfl_xor(p, 4);
            float mn = fmaxf(m, p);
            float sc = __expf(m - mn);
            float pw = __expf(p - mn);
            lsum = lsum * sc + pw;
#pragma unroll
            for (int i = 0; i < 8; i++) acc[i] = acc[i] * sc + pw * xl[i];
            m = mn;
        }
        float inv = 1.0f / (lsum + 1e-16f);
#pragma unroll
        for (int i = 0; i < 8; i++) {
            float v = acc[i] * inv;
            acc[i] = 0.5f * (v + __shfl_xor(v, 8));  // head average
        }
        if (q < 8) {
            float4 w0, w1;
#pragma unroll
            for (int i = 0; i < 8; i++) {
                float c = acc[i] + cbv[i];
                sacc[i] += c; qacc[i] += c * c;
                if (i < 4) (&w0.x)[i] = c; else (&w1.x)[i - 4] = c;
            }
            *(float4*)(g + (size_t)d * 64 + 8 * q) = w0;
            *(float4*)(g + (size_t)d * 64 + 8 * q + 4) = w1;
        }
    }
    if (q < 8) {
#pragma unroll
        for (int i = 0; i < 8; i++) {
            atomicAdd(&ls[8 * q + i], sacc[i]);
            atomicAdd(&lq[8 * q + i], qacc[i]);
        }
    }
    __syncthreads();
    float* bb = bns + (blockIdx.x & (NREP - 1)) * 128;
    if (t < 64) atomicAdd(&bb[t], ls[t]);
    else if (t < 128) atomicAdd(&bb[t], lq[t - 64]);
}

// ---- fold layer-12 bns replicas (one-off) ----
__global__ void k_fold(const float* __restrict__ bns, float* __restrict__ bout) {
    int t = threadIdx.x;
    if (t < 128) {
        float s = 0.f;
#pragma unroll
        for (int r = 0; r < NREP; r++) s += bns[r * 128 + t];
        bout[t] = s;
    }
}

// ---- final BN+ELU+residual (layer 12), h only ----
__global__ void k_bnfinal(const float* __restrict__ g, const float* __restrict__ bns,
                          const float* __restrict__ gamma, const float* __restrict__ beta, float* h) {
    int t = blockIdx.x * blockDim.x + threadIdx.x;
    if (t >= NN * 16) return;
    int c4 = (t & 15) * 4;
    float4 gg = *(const float4*)(g + (size_t)t * 4);
    float4 out;
#pragma unroll
    for (int r = 0; r < 4; r++) {
        int c = c4 + r;
        float mean = bns[c] * (1.0f / NN);
        float var = bns[64 + c] * (1.0f / NN) - mean * mean;
        var = fmaxf(var, 0.f);
        float rstd = rsqrtf(var + EPS_BN);
        float v = ((&gg.x)[r] - mean) * rstd * gamma[c] + beta[c];
        (&out.x)[r] = v > 0.f ? v : (__expf(v) - 1.f);
    }
    float4 hh = *(const float4*)(h + (size_t)t * 4);
    out.x += hh.x; out.y += hh.y; out.z += hh.z; out.w += hh.w;
    *(float4*)(h + (size_t)t * 4) = out;
}

// ---- output head ----
__global__ void k_head(const float* __restrict__ h, const float* __restrict__ W1, const float* __restrict__ b1,
                       const float* __restrict__ W2, const float* __restrict__ b2, float* __restrict__ out) {
    int t = blockIdx.x * blockDim.x + threadIdx.x;
    int node = t >> 5;
    int j = t & 31;
    if (node >= NN) return;
    float acc = b1[j];
    const float* hr = h + (size_t)node * 64;
#pragma unroll
    for (int k = 0; k < 64; k++) acc += hr[k] * W1[k * 32 + j];
    float e = acc > 0.f ? acc : (__expf(acc) - 1.f);
    float z = e * W2[j];
    z += __shfl_xor(z, 1); z += __shfl_xor(z, 2); z += __shfl_xor(z, 4);
    z += __shfl_xor(z, 8); z += __shfl_xor(z, 16);
    if (j == 0) {
        float y = z + b2[0];
        out[node] = 1.0f / (1.0f + __expf(-y));
    }
}

extern "C" void kernel_launch(void* const* d_in, const int* in_sizes, int n_in,
                              void* d_out, int out_size, void* d_ws, size_t ws_size,
                              hipStream_t stream) {
    const float* x = (const float*)d_in[0];
    const int* ei = (const int*)d_in[1];
    const float* inW = (const float*)d_in[2];
    const float* inb = (const float*)d_in[3];
    const float* ing = (const float*)d_in[4];
    const float* inbeta = (const float*)d_in[5];
    const float* Wl = (const float*)d_in[6];
    const float* Wr = (const float*)d_in[7];
    const float* att = (const float*)d_in[8];
    const float* cb = (const float*)d_in[9];
    const float* bng = (const float*)d_in[10];
    const float* bnb = (const float*)d_in[11];
    const float* W1 = (const float*)d_in[12];
    const float* b1 = (const float*)d_in[13];
    const float* W2 = (const float*)d_in[14];
    const float* b2 = (const float*)d_in[15];
    float* out = (float*)d_out;

    char* ws = (char*)d_ws;
    size_t off = 0;
    auto alloc = [&](size_t bytes) -> char* {
        char* p = ws + off;
        off = (off + bytes + 255) & ~(size_t)255;
        return p;
    };
    float* h    = (float*)alloc((size_t)NN * 64 * 4);
    float* g    = (float*)alloc((size_t)NN * 64 * 4);
    u16* xlxr   = (u16*)alloc((size_t)NN * 256 * 2);
    u16* WThi   = (u16*)alloc((size_t)NLAYERS * 256 * 64 * 2);
    u16* WTlo   = (u16*)alloc((size_t)NLAYERS * 256 * 64 * 2);
    int* deg    = (int*)alloc((size_t)NN * 4);
    int* rp     = (int*)alloc((size_t)(NN + 1) * 4);
    int* cur    = (int*)alloc((size_t)NN * 4);
    int* colv   = (int*)alloc((size_t)NET * 4);
    int* stmp   = (int*)alloc((size_t)NN * 4);
    int* part   = (int*)alloc(256 * 4);
    float* bns  = (float*)alloc((size_t)(NLAYERS + 1) * NREP * 128 * 4);
    float* bnsf = (float*)alloc(128 * 4);

    k_zero_i<<<(NN + 255) / 256, 256, 0, stream>>>(deg, NN);
    k_zero_f<<<((NLAYERS + 1) * NREP * 128 + 255) / 256, 256, 0, stream>>>(bns, (NLAYERS + 1) * NREP * 128);

    k_wt<<<(NLAYERS * 256 * HIDC + 255) / 256, 256, 0, stream>>>(Wl, Wr, WThi, WTlo);
    k_count<<<(NE + 255) / 256, 256, 0, stream>>>(ei, deg);
    k_scan1<<<196, 256, 0, stream>>>(deg, stmp, part);
    k_scan2<<<1, 256, 0, stream>>>(part);
    k_scan3<<<196, 256, 0, stream>>>(deg, stmp, part, rp, cur);
    k_scatter<<<(NET + 255) / 256, 256, 0, stream>>>(ei, cur, colv);

    k_inproj<<<512, 256, 0, stream>>>(x, inW, inb, g, bns);

    for (int i = 0; i < NLAYERS; i++) {
        const float* gamma = (i == 0) ? ing : bng + (size_t)(i - 1) * 64;
        const float* beta  = (i == 0) ? inbeta : bnb + (size_t)(i - 1) * 64;
        k_gemmbn<<<3125, 256, 0, stream>>>(g, bns + (size_t)i * NREP * 128, gamma, beta, h, (i > 0) ? 1 : 0,
                                           WThi + (size_t)i * 16384, WTlo + (size_t)i * 16384, xlxr);
        k_edge<<<1563, 256, 0, stream>>>((const uint4*)xlxr, rp, colv,
                                         att + (size_t)i * 128, cb + (size_t)i * 64,
                                         g, bns + (size_t)(i + 1) * NREP * 128);
    }
    k_fold<<<1, 128, 0, stream>>>(bns + (size_t)NLAYERS * NREP * 128, bnsf);
    k_bnfinal<<<3125, 256, 0, stream>>>(g, bnsf,
                                        bng + (size_t)(NLAYERS - 1) * 64, bnb + (size_t)(NLAYERS - 1) * 64, h);
    k_head<<<6250, 256, 0, stream>>>(h, W1, b1, W2, b2, out);
}

// Round 12
// 1065.719 us; speedup vs baseline: 1.6448x; 1.1229x over previous
//
#include <hip/hip_runtime.h>

#define NN 50000
#define F_IN 17
#define HIDC 64
#define NLAYERS 12
#define NE 400000
#define NET (NE + NN)
#define EPS_BN 1e-5f
#define NREP 8   // bns replicas to spread same-address atomic contention

typedef unsigned short u16;
typedef __bf16 bf16x8 __attribute__((ext_vector_type(8)));
typedef float f32x4 __attribute__((ext_vector_type(4)));

__device__ __forceinline__ float bf2f(u16 v) {
    union { unsigned int i; float f; } u; u.i = ((unsigned int)v) << 16; return u.f;
}
__device__ __forceinline__ u16 f2bf(float f) {
    union { float f; unsigned int i; } u; u.f = f;
    unsigned int r = u.i + 0x7fffu + ((u.i >> 16) & 1u);
    return (u16)(r >> 16);
}
__device__ __forceinline__ float2 bf2x(unsigned int w) {
    union { unsigned int i; float f; } a, b;
    a.i = w << 16; b.i = w & 0xffff0000u;
    float2 r; r.x = a.f; r.y = b.f; return r;
}
__device__ __forceinline__ void unpack8(uint4 w, float* f) {
    float2 a = bf2x(w.x), b = bf2x(w.y), c = bf2x(w.z), d = bf2x(w.w);
    f[0] = a.x; f[1] = a.y; f[2] = b.x; f[3] = b.y;
    f[4] = c.x; f[5] = c.y; f[6] = d.x; f[7] = d.y;
}

__global__ void k_zero_i(int* __restrict__ p, int n) {
    int i = blockIdx.x * blockDim.x + threadIdx.x;
    if (i < n) p[i] = 0;
}
__global__ void k_zero_f(float* __restrict__ p, int n) {
    int i = blockIdx.x * blockDim.x + threadIdx.x;
    if (i < n) p[i] = 0.f;
}

// ---- transposed split-bf16 concat weights ----
__global__ void k_wt(const float* __restrict__ Wl, const float* __restrict__ Wr,
                     u16* __restrict__ WThi, u16* __restrict__ WTlo) {
    int t = blockIdx.x * blockDim.x + threadIdx.x;
    if (t >= NLAYERS * 256 * HIDC) return;
    int k = t & 63, j = (t >> 6) & 255, i = t >> 14;
    int jj = (j < 128) ? j : (j - 128);
    float v = (j < 128) ? Wl[(i * HIDC + k) * 128 + jj] : Wr[(i * HIDC + k) * 128 + jj];
    u16 hi = f2bf(v);
    u16 lo = f2bf(v - bf2f(hi));
    WThi[t] = hi; WTlo[t] = lo;
}

// ---- CSR build ----
__global__ void k_count(const int* __restrict__ ei, int* __restrict__ deg) {
    int e = blockIdx.x * blockDim.x + threadIdx.x;
    if (e < NE) {
        int d = ei[NE + e];
        if ((unsigned)d < NN) atomicAdd(&deg[d], 1);
    }
}

__global__ void k_scan1(const int* __restrict__ deg, int* __restrict__ tmp, int* __restrict__ part) {
    __shared__ int s[256];
    int b = blockIdx.x, t = threadIdx.x;
    int n = b * 256 + t;
    int v = (n < NN) ? deg[n] + 1 : 0;
    s[t] = v; __syncthreads();
    for (int o = 1; o < 256; o <<= 1) {
        int a = s[t];
        int w = (t >= o) ? s[t - o] : 0;
        __syncthreads();
        s[t] = a + w;
        __syncthreads();
    }
    if (n < NN) tmp[n] = s[t];
    if (t == 255) part[b] = s[255];
}
__global__ void k_scan2(int* __restrict__ part) {
    __shared__ int s[256];
    int t = threadIdx.x;
    int v = (t < 196) ? part[t] : 0;
    s[t] = v; __syncthreads();
    for (int o = 1; o < 256; o <<= 1) {
        int a = s[t];
        int w = (t >= o) ? s[t - o] : 0;
        __syncthreads();
        s[t] = a + w;
        __syncthreads();
    }
    if (t < 196) part[t] = s[t] - v;
    if (t == 195) part[196] = s[195];
}
__global__ void k_scan3(const int* __restrict__ deg, const int* __restrict__ tmp,
                        const int* __restrict__ part, int* __restrict__ rp, int* __restrict__ cur) {
    int b = blockIdx.x, t = threadIdx.x;
    int n = b * 256 + t;
    if (n < NN) {
        int e = tmp[n] - (deg[n] + 1) + part[b];
        rp[n] = e; cur[n] = e;
    }
    if (n == 0) rp[NN] = part[196];
}

__global__ void k_scatter(const int* __restrict__ ei, int* __restrict__ cur, int* __restrict__ col) {
    int e = blockIdx.x * blockDim.x + threadIdx.x;
    if (e >= NET) return;
    int s, d;
    if (e < NE) { s = ei[e]; d = ei[NE + e]; } else { s = d = e - NE; }
    if ((unsigned)s >= NN) s = 0;
    if ((unsigned)d >= NN) d = 0;
    int p = atomicAdd(&cur[d], 1);
    if ((unsigned)p < NET) col[p] = s;
}

// ---- input projection + BN partial sums (into replica 0) ----
__global__ void k_inproj(const float* __restrict__ x, const float* __restrict__ W, const float* __restrict__ b,
                         float* __restrict__ g, float* __restrict__ bns) {
    __shared__ float ls[64], lq[64];
    int t = threadIdx.x;
    if (t < 64) { ls[t] = 0.f; lq[t] = 0.f; }
    __syncthreads();
    int j = t & 63;
    float wcol[F_IN];
#pragma unroll
    for (int k = 0; k < F_IN; k++) wcol[k] = W[k * 64 + j];
    float bias = b[j];
    float sA = 0.f, sQ = 0.f;
    for (int idx = blockIdx.x * blockDim.x + t; idx < NN * 64; idx += gridDim.x * blockDim.x) {
        int node = idx >> 6;
        float acc = bias;
#pragma unroll
        for (int k = 0; k < F_IN; k++) acc += x[node * F_IN + k] * wcol[k];
        g[idx] = acc;
        sA += acc; sQ += acc * acc;
    }
    atomicAdd(&ls[j], sA); atomicAdd(&lq[j], sQ);
    __syncthreads();
    if (t < 64) atomicAdd(&bns[t], ls[t]);
    else if (t < 128) atomicAdd(&bns[t], lq[t - 64]);
}

// ---- fused BN+ELU+residual prologue + xl|xr MFMA GEMM, 64-node tiles ----
// grid 782: block = 64 nodes x 256 cols; B-fragments amortized over 4 node-tiles
#define LDP 72
__global__ __launch_bounds__(256) void k_gemmbn(const float* __restrict__ g, const float* __restrict__ bns,
                                                const float* __restrict__ gamma, const float* __restrict__ beta,
                                                float* h, int residual,
                                                const u16* __restrict__ WThi, const u16* __restrict__ WTlo,
                                                u16* __restrict__ xlxr) {
    __shared__ u16 shi[64 * LDP];
    __shared__ u16 slo[64 * LDP];
    __shared__ float sbn[128];
    int t = threadIdx.x;
    int node0 = blockIdx.x * 64;
    int lane = t & 63, wv = t >> 6;
    int ml = lane & 15, kb = (lane >> 4) * 8;
    // fold bns replicas into LDS
    if (t < 128) {
        float s = 0.f;
#pragma unroll
        for (int r = 0; r < NREP; r++) s += bns[r * 128 + t];
        sbn[t] = s;
    }
    // B fragments for this wave's 4 col-tiles (reused across all 4 node-tiles)
    bf16x8 bh[4][2], bl[4][2];
#pragma unroll
    for (int c = 0; c < 4; c++) {
        int col0 = (wv * 4 + c) * 16;
        size_t brow = (size_t)(col0 + ml) * 64 + kb;
        bh[c][0] = *(const bf16x8*)(WThi + brow);
        bh[c][1] = *(const bf16x8*)(WThi + brow + 32);
        bl[c][0] = *(const bf16x8*)(WTlo + brow);
        bl[c][1] = *(const bf16x8*)(WTlo + brow + 32);
    }
    __syncthreads();
    // BN+ELU+residual for 64 nodes: thread handles node r*16+(t>>4), ch (t&15)*4
#pragma unroll
    for (int r = 0; r < 4; r++) {
        int nd = r * 16 + (t >> 4);
        int ch = (t & 15) * 4;
        int node = node0 + nd;
        float4 out = {0.f, 0.f, 0.f, 0.f};
        if (node < NN) {
            size_t gpos = (size_t)node * 64 + ch;
            float4 gg = *(const float4*)(g + gpos);
#pragma unroll
            for (int rr = 0; rr < 4; rr++) {
                int c = ch + rr;
                float mean = sbn[c] * (1.0f / NN);
                float var = sbn[64 + c] * (1.0f / NN) - mean * mean;
                var = fmaxf(var, 0.f);
                float rstd = rsqrtf(var + EPS_BN);
                float v = ((&gg.x)[rr] - mean) * rstd * gamma[c] + beta[c];
                (&out.x)[rr] = v > 0.f ? v : (__expf(v) - 1.f);
            }
            if (residual) {
                float4 hh = *(const float4*)(h + gpos);
                out.x += hh.x; out.y += hh.y; out.z += hh.z; out.w += hh.w;
            }
            *(float4*)(h + gpos) = out;
        }
        ushort4 phi, plo;
#pragma unroll
        for (int rr = 0; rr < 4; rr++) {
            float v = (&out.x)[rr];
            u16 hi = f2bf(v);
            u16 lo = f2bf(v - bf2f(hi));
            (&phi.x)[rr] = hi; (&plo.x)[rr] = lo;
        }
        *(ushort4*)(shi + nd * LDP + ch) = phi;
        *(ushort4*)(slo + nd * LDP + ch) = plo;
    }
    __syncthreads();
    // 4 node-tiles x 4 col-tiles MFMA
#pragma unroll
    for (int nt = 0; nt < 4; nt++) {
        int arow = (nt * 16 + ml) * LDP + kb;
        bf16x8 ah0 = *(const bf16x8*)(shi + arow);
        bf16x8 ah1 = *(const bf16x8*)(shi + arow + 32);
        bf16x8 al0 = *(const bf16x8*)(slo + arow);
        bf16x8 al1 = *(const bf16x8*)(slo + arow + 32);
        int rowb = node0 + nt * 16 + (lane >> 4) * 4;
#pragma unroll
        for (int c = 0; c < 4; c++) {
            f32x4 acc = {0.f, 0.f, 0.f, 0.f};
            acc = __builtin_amdgcn_mfma_f32_16x16x32_bf16(al0, bh[c][0], acc, 0, 0, 0);
            acc = __builtin_amdgcn_mfma_f32_16x16x32_bf16(al1, bh[c][1], acc, 0, 0, 0);
            acc = __builtin_amdgcn_mfma_f32_16x16x32_bf16(ah0, bl[c][0], acc, 0, 0, 0);
            acc = __builtin_amdgcn_mfma_f32_16x16x32_bf16(ah1, bl[c][1], acc, 0, 0, 0);
            acc = __builtin_amdgcn_mfma_f32_16x16x32_bf16(ah0, bh[c][0], acc, 0, 0, 0);
            acc = __builtin_amdgcn_mfma_f32_16x16x32_bf16(ah1, bh[c][1], acc, 0, 0, 0);
            int colj = (wv * 4 + c) * 16 + ml;
#pragma unroll
            for (int r = 0; r < 4; r++)
                if (rowb + r < NN) xlxr[(size_t)(rowb + r) * 256 + colj] = f2bf(acc[r]);
        }
    }
}

// ---- GATv2 attention (r9-exact): 16-lane subset per dst slot, ONLINE softmax
//      (max-subtraction is REQUIRED: direct-exp breaks on very-negative-score dsts
//       via the +1e-16 epsilon and clamping breaks genuine large-score ratios),
//      replicated bns atomics ----
__global__ __launch_bounds__(256) void k_edge(const uint4* __restrict__ xw4, const int* __restrict__ rp,
                                              const int* __restrict__ col, const float* __restrict__ attL,
                                              const float* __restrict__ cbL, float* __restrict__ g,
                                              float* __restrict__ bns) {
    __shared__ float ls[64], lq[64];
    int t = threadIdx.x;
    if (t < 64) { ls[t] = 0.f; lq[t] = 0.f; }
    __syncthreads();
    int lane = t & 63;
    int q = lane & 15;
    int gsub = lane >> 4;
    int slot = (blockIdx.x * 4 + (t >> 6)) * 4 + gsub;
    int nslot = gridDim.x * 16;
    float atv[8];
#pragma unroll
    for (int i = 0; i < 8; i++) atv[i] = attL[8 * q + i];
    float cbv[8];
#pragma unroll
    for (int i = 0; i < 8; i++) cbv[i] = 0.f;
    if (q < 8) {
#pragma unroll
        for (int i = 0; i < 8; i++) cbv[i] = cbL[8 * q + i];
    }
    float sacc[8], qacc[8];
#pragma unroll
    for (int i = 0; i < 8; i++) { sacc[i] = 0.f; qacc[i] = 0.f; }
    for (int d = slot; d < NN; d += nslot) {
        float xr[8];
        { uint4 w = xw4[(size_t)d * 32 + 16 + q]; unpack8(w, xr); }
        int beg = rp[d], end = rp[d + 1];
        float m = -1e30f, lsum = 0.f;
        float acc[8];
#pragma unroll
        for (int i = 0; i < 8; i++) acc[i] = 0.f;
        int s0 = col[beg];  // deg >= 1 guaranteed (self-loop)
        uint4 xlw = xw4[(size_t)s0 * 32 + q];
        for (int idx = beg; idx < end; idx++) {
            uint4 curw = xlw;
            if (idx + 1 < end) {
                int s2 = col[idx + 1];
                xlw = xw4[(size_t)s2 * 32 + q];
            }
            float xl[8]; unpack8(curw, xl);
            float p = 0.f;
#pragma unroll
            for (int i = 0; i < 8; i++) {
                float u = xl[i] + xr[i];
                float lr = u > 0.f ? u : 0.2f * u;
                p += lr * atv[i];
            }
            p += __shfl_xor(p, 1); p += __shfl_xor(p, 2); p += __shfl_xor(p, 4);
            float mn = fmaxf(m, p);
            float sc = __expf(m - mn);
            float pw = __expf(p - mn);
            lsum = lsum * sc + pw;
#pragma unroll
            for (int i = 0; i < 8; i++) acc[i] = acc[i] * sc + pw * xl[i];
            m = mn;
        }
        float inv = 1.0f / (lsum + 1e-16f);
#pragma unroll
        for (int i = 0; i < 8; i++) {
            float v = acc[i] * inv;
            acc[i] = 0.5f * (v + __shfl_xor(v, 8));  // head average
        }
        if (q < 8) {
            float4 w0, w1;
#pragma unroll
            for (int i = 0; i < 8; i++) {
                float c = acc[i] + cbv[i];
                sacc[i] += c; qacc[i] += c * c;
                if (i < 4) (&w0.x)[i] = c; else (&w1.x)[i - 4] = c;
            }
            *(float4*)(g + (size_t)d * 64 + 8 * q) = w0;
            *(float4*)(g + (size_t)d * 64 + 8 * q + 4) = w1;
        }
    }
    if (q < 8) {
#pragma unroll
        for (int i = 0; i < 8; i++) {
            atomicAdd(&ls[8 * q + i], sacc[i]);
            atomicAdd(&lq[8 * q + i], qacc[i]);
        }
    }
    __syncthreads();
    float* bb = bns + (blockIdx.x & (NREP - 1)) * 128;
    if (t < 64) atomicAdd(&bb[t], ls[t]);
    else if (t < 128) atomicAdd(&bb[t], lq[t - 64]);
}

// ---- fold layer-12 bns replicas (one-off) ----
__global__ void k_fold(const float* __restrict__ bns, float* __restrict__ bout) {
    int t = threadIdx.x;
    if (t < 128) {
        float s = 0.f;
#pragma unroll
        for (int r = 0; r < NREP; r++) s += bns[r * 128 + t];
        bout[t] = s;
    }
}

// ---- final BN+ELU+residual (layer 12), h only ----
__global__ void k_bnfinal(const float* __restrict__ g, const float* __restrict__ bns,
                          const float* __restrict__ gamma, const float* __restrict__ beta, float* h) {
    int t = blockIdx.x * blockDim.x + threadIdx.x;
    if (t >= NN * 16) return;
    int c4 = (t & 15) * 4;
    float4 gg = *(const float4*)(g + (size_t)t * 4);
    float4 out;
#pragma unroll
    for (int r = 0; r < 4; r++) {
        int c = c4 + r;
        float mean = bns[c] * (1.0f / NN);
        float var = bns[64 + c] * (1.0f / NN) - mean * mean;
        var = fmaxf(var, 0.f);
        float rstd = rsqrtf(var + EPS_BN);
        float v = ((&gg.x)[r] - mean) * rstd * gamma[c] + beta[c];
        (&out.x)[r] = v > 0.f ? v : (__expf(v) - 1.f);
    }
    float4 hh = *(const float4*)(h + (size_t)t * 4);
    out.x += hh.x; out.y += hh.y; out.z += hh.z; out.w += hh.w;
    *(float4*)(h + (size_t)t * 4) = out;
}

// ---- output head ----
__global__ void k_head(const float* __restrict__ h, const float* __restrict__ W1, const float* __restrict__ b1,
                       const float* __restrict__ W2, const float* __restrict__ b2, float* __restrict__ out) {
    int t = blockIdx.x * blockDim.x + threadIdx.x;
    int node = t >> 5;
    int j = t & 31;
    if (node >= NN) return;
    float acc = b1[j];
    const float* hr = h + (size_t)node * 64;
#pragma unroll
    for (int k = 0; k < 64; k++) acc += hr[k] * W1[k * 32 + j];
    float e = acc > 0.f ? acc : (__expf(acc) - 1.f);
    float z = e * W2[j];
    z += __shfl_xor(z, 1); z += __shfl_xor(z, 2); z += __shfl_xor(z, 4);
    z += __shfl_xor(z, 8); z += __shfl_xor(z, 16);
    if (j == 0) {
        float y = z + b2[0];
        out[node] = 1.0f / (1.0f + __expf(-y));
    }
}

extern "C" void kernel_launch(void* const* d_in, const int* in_sizes, int n_in,
                              void* d_out, int out_size, void* d_ws, size_t ws_size,
                              hipStream_t stream) {
    const float* x = (const float*)d_in[0];
    const int* ei = (const int*)d_in[1];
    const float* inW = (const float*)d_in[2];
    const float* inb = (const float*)d_in[3];
    const float* ing = (const float*)d_in[4];
    const float* inbeta = (const float*)d_in[5];
    const float* Wl = (const float*)d_in[6];
    const float* Wr = (const float*)d_in[7];
    const float* att = (const float*)d_in[8];
    const float* cb = (const float*)d_in[9];
    const float* bng = (const float*)d_in[10];
    const float* bnb = (const float*)d_in[11];
    const float* W1 = (const float*)d_in[12];
    const float* b1 = (const float*)d_in[13];
    const float* W2 = (const float*)d_in[14];
    const float* b2 = (const float*)d_in[15];
    float* out = (float*)d_out;

    char* ws = (char*)d_ws;
    size_t off = 0;
    auto alloc = [&](size_t bytes) -> char* {
        char* p = ws + off;
        off = (off + bytes + 255) & ~(size_t)255;
        return p;
    };
    float* h    = (float*)alloc((size_t)NN * 64 * 4);
    float* g    = (float*)alloc((size_t)NN * 64 * 4);
    u16* xlxr   = (u16*)alloc((size_t)NN * 256 * 2);
    u16* WThi   = (u16*)alloc((size_t)NLAYERS * 256 * 64 * 2);
    u16* WTlo   = (u16*)alloc((size_t)NLAYERS * 256 * 64 * 2);
    int* deg    = (int*)alloc((size_t)NN * 4);
    int* rp     = (int*)alloc((size_t)(NN + 1) * 4);
    int* cur    = (int*)alloc((size_t)NN * 4);
    int* colv   = (int*)alloc((size_t)NET * 4);
    int* stmp   = (int*)alloc((size_t)NN * 4);
    int* part   = (int*)alloc(256 * 4);
    float* bns  = (float*)alloc((size_t)(NLAYERS + 1) * NREP * 128 * 4);
    float* bnsf = (float*)alloc(128 * 4);

    k_zero_i<<<(NN + 255) / 256, 256, 0, stream>>>(deg, NN);
    k_zero_f<<<((NLAYERS + 1) * NREP * 128 + 255) / 256, 256, 0, stream>>>(bns, (NLAYERS + 1) * NREP * 128);

    k_wt<<<(NLAYERS * 256 * HIDC + 255) / 256, 256, 0, stream>>>(Wl, Wr, WThi, WTlo);
    k_count<<<(NE + 255) / 256, 256, 0, stream>>>(ei, deg);
    k_scan1<<<196, 256, 0, stream>>>(deg, stmp, part);
    k_scan2<<<1, 256, 0, stream>>>(part);
    k_scan3<<<196, 256, 0, stream>>>(deg, stmp, part, rp, cur);
    k_scatter<<<(NET + 255) / 256, 256, 0, stream>>>(ei, cur, colv);

    k_inproj<<<512, 256, 0, stream>>>(x, inW, inb, g, bns);

    for (int i = 0; i < NLAYERS; i++) {
        const float* gamma = (i == 0) ? ing : bng + (size_t)(i - 1) * 64;
        const float* beta  = (i == 0) ? inbeta : bnb + (size_t)(i - 1) * 64;
        k_gemmbn<<<782, 256, 0, stream>>>(g, bns + (size_t)i * NREP * 128, gamma, beta, h, (i > 0) ? 1 : 0,
                                          WThi + (size_t)i * 16384, WTlo + (size_t)i * 16384, xlxr);
        k_edge<<<1563, 256, 0, stream>>>((const uint4*)xlxr, rp, colv,
                                         att + (size_t)i * 128, cb + (size_t)i * 64,
                                         g, bns + (size_t)(i + 1) * NREP * 128);
    }
    k_fold<<<1, 128, 0, stream>>>(bns + (size_t)NLAYERS * NREP * 128, bnsf);
    k_bnfinal<<<3125, 256, 0, stream>>>(g, bnsf,
                                        bng + (size_t)(NLAYERS - 1) * 64, bnb + (size_t)(NLAYERS - 1) * 64, h);
    k_head<<<6250, 256, 0, stream>>>(h, W1, b1, W2, b2, out);
}